// Round 4
// baseline (738.199 us; speedup 1.0000x reference)
//
#include <hip/hip_runtime.h>
#include <math.h>

#define BATCH 8
#define N_ANCH 76725
#define NCLS 80
#define NDET 100
#define NPRED 84
#define BCAP 1216   // bucket capacity: mean 959, sd 31, E[max of 640] ~1070 -> +8 sigma
#define KMAX 19     // BCAP / 64
#define CURSOR_STRIDE 16  // one counter per 64B line (round-2 fix: same-line atomic
                          // serialization was ~450us of wall)

typedef unsigned long long u64;
typedef unsigned int u32;

// ---------------------------------------------------------------------------
// K1 (fused, coalesced): 4 lanes per anchor. Lane p of a 4-lane group reads
// float4 indices {p, p+4, p+8, ...} of the 84-float row, so for each load
// step the wave issues 16 fully-used contiguous 64B segments. Per-lane
// partial top-2 over logits is merged to the exact lexicographic
// (logit desc, class asc) top-2 via two shfl_xor steps — bitwise-identical
// semantics to a sequential strict-> scan, including the sigmoid-rounding
// tie window. Lane p==0 decodes the box and scatters into the (batch,class)
// bucket. Cursor counters padded to one per 64B line.
// ---------------------------------------------------------------------------
__global__ void __launch_bounds__(256) k_decode_scatter(
    const float* __restrict__ pred, const float* __restrict__ anchors,
    int* __restrict__ cursor, float4* __restrict__ bk_c,
    float* __restrict__ bk_s, int* __restrict__ bk_oi) {
#pragma clang fp contract(off)
  int lane = threadIdx.x & 63;
  int wave = threadIdx.x >> 6;
  int g = lane >> 2;   // anchor within wave (16 per wave)
  int p = lane & 3;    // sub-lane within anchor group
  int gid = blockIdx.x * 64 + wave * 16 + g;  // 64 anchors per block
  if (gid >= BATCH * N_ANCH) return;
  int b = gid / N_ANCH;
  int i = gid - b * N_ANCH;
  const float4* row = (const float4*)(pred + (size_t)gid * NPRED);

  // per-lane partial top-2 (strict > keeps smallest class index on ties;
  // within a lane, class indices are visited in ascending order)
  float l1 = -3.0e38f, l2 = -3.0e38f;
  int i1 = 0, i2 = 0;
#define UPD(LV, IDX)                                          \
  { float l = (LV); int idx = (IDX);                          \
    if (l > l1) { l2 = l1; i2 = i1; l1 = l; i1 = idx; }       \
    else if (l > l2) { l2 = l; i2 = idx; } }

  float4 bp = make_float4(0.f, 0.f, 0.f, 0.f);
  {
    float4 v = row[p];  // j=0: p==0 gets the box quad, p>0 get class quads
    if (p == 0) {
      bp = v;
    } else {
      int c0 = p * 4 - 4;
      UPD(v.x, c0) UPD(v.y, c0 + 1) UPD(v.z, c0 + 2) UPD(v.w, c0 + 3)
    }
  }
#pragma unroll
  for (int j = 1; j < 5; ++j) {
    int idx = p + 4 * j;
    float4 v = row[idx];
    int c0 = idx * 4 - 4;
    UPD(v.x, c0) UPD(v.y, c0 + 1) UPD(v.z, c0 + 2) UPD(v.w, c0 + 3)
  }
  if (p == 0) {  // tail quad idx=20 (classes 76..79)
    float4 v = row[20];
    UPD(v.x, 76) UPD(v.y, 77) UPD(v.z, 78) UPD(v.w, 79)
  }
#undef UPD

  // exact lex top-2 merge across the 4-lane group (classes are disjoint
  // across lanes, so union-top2 = merge of per-lane sorted top2 pairs)
#pragma unroll
  for (int off = 1; off <= 2; off <<= 1) {
    float ol1 = __shfl_xor(l1, off);
    int   oj1 = __shfl_xor(i1, off);
    float ol2 = __shfl_xor(l2, off);
    int   oj2 = __shfl_xor(i2, off);
    bool aW = (l1 > ol1) || (l1 == ol1 && i1 < oj1);
    float w1 = aW ? l1 : ol1;  int wi1 = aW ? i1 : oj1;
    float ca = aW ? l2 : ol2;  int cai = aW ? i2 : oj2;  // winner's 2nd
    float cb = aW ? ol1 : l1;  int cbi = aW ? oj1 : i1;  // loser's 1st
    bool s2 = (ca > cb) || (ca == cb && cai < cbi);
    l1 = w1; i1 = wi1;
    l2 = s2 ? ca : cb; i2 = s2 ? cai : cbi;
  }

  if (p != 0) return;  // group leader emits

  float conf = 1.0f / (1.0f + expf(-l1));
  int cls = i1;
  if (l1 - l2 < 1e-4f) {  // only window where rounded sigmoids can collide
    float conf2 = 1.0f / (1.0f + expf(-l2));
    if (conf2 > conf) { conf = conf2; cls = i2; }
    else if (conf2 == conf && i2 < i1) { cls = i2; }
  }
  float score = (conf > 0.05f) ? conf : -1.0f;

  // box decode (reference op order, no fma contraction)
  float4 a = *(const float4*)(anchors + (size_t)i * 4);
  float b0 = bp.x * 0.1f, b1 = bp.y * 0.1f, b2 = bp.z * 0.2f, b3 = bp.w * 0.2f;
  float cx = b0 * a.z + a.x;
  float cy = b1 * a.w + a.y;
  float w = expf(b2) * a.z;
  float h = expf(b3) * a.w;
  float offv = (float)cls * 10000.0f;
  float x0 = (cx - 0.5f * w) + offv, y0 = (cy - 0.5f * h) + offv;
  float x1 = (cx + 0.5f * w) + offv, y1 = (cy + 0.5f * h) + offv;

  int bc = b * NCLS + cls;
  int slot = atomicAdd(&cursor[bc * CURSOR_STRIDE], 1);
  if (slot < BCAP) {
    size_t idxo = (size_t)bc * BCAP + slot;
    bk_c[idxo] = make_float4(x0, y0, x1, y1);
    bk_s[idxo] = score;
    bk_oi[idxo] = i;
  }
}

// ---------------------------------------------------------------------------
// K2: per-(batch,class) greedy NMS. One wave per block; wall time is the
// serial per-bucket chain, so everything is tuned for chain latency:
//  - (score, oidx) packed into ONE u64 key (output encoding: score<<32|~oidx).
//    Lex-argmax == u64 max; dead = 0; termination = max == 0. Keys are the
//    ONLY per-lane register array (38 VGPRs) — fits, no scratch.
//  - Round-3 lesson: adding q[19] float4 + a2[19] register arrays demanded
//    ~180 VGPRs, compiler allocated 104 -> boxes spilled to SCRATCH and every
//    iteration paid ~19 scratch reloads on the chain (255us, VALUBusy 27%).
//    Boxes live in LDS; suppress loop reads lc[lid+64k] at static offsets
//    (independent ds_read_b128, off-chain); a2 recomputed inline (2 VALU).
//  - All array indices compile-time constant; winner-kill is a static-index
//    predicate fused into the suppress loop.
// ---------------------------------------------------------------------------
__global__ void __launch_bounds__(64, 1) k_nms_class(
    const int* __restrict__ cursor, const float4* __restrict__ bk_c,
    const float* __restrict__ bk_s, const int* __restrict__ bk_oi,
    u64* __restrict__ keys, int* __restrict__ nsel) {
#pragma clang fp contract(off)
  __shared__ float4 lc[BCAP];  // 19.5 KB
  int bc = blockIdx.x;
  int lid = threadIdx.x;
  int cnt = cursor[bc * CURSOR_STRIDE];
  cnt = (cnt > BCAP) ? BCAP : cnt;
  size_t base = (size_t)bc * BCAP;

  u64 key[KMAX];
#pragma unroll
  for (int k = 0; k < KMAX; ++k) {
    int j = lid + 64 * k;
    bool v = j < cnt;
    float s = v ? bk_s[base + j] : -1.0f;
    u32 o = v ? (u32)bk_oi[base + j] : 0u;
    float4 c = v ? bk_c[base + j] : make_float4(0.f, 0.f, 0.f, 0.f);
    key[k] = (s > 0.0f)
                 ? (((u64)__float_as_uint(s) << 32) | (u64)(0xFFFFFFFFu - o))
                 : 0ULL;
    lc[j] = c;  // KMAX*64 == BCAP: every slot written
  }
  __syncthreads();

  u64* ok = keys + (size_t)bc * NDET;
  int t = 0;
  for (;;) {
    // static-index tree argmax over the 19 register keys (depth 5)
    u64 tk[10];
    int ts[10];
#pragma unroll
    for (int k = 0; k < 9; ++k) {
      bool gr = key[2 * k + 1] > key[2 * k];
      tk[k] = gr ? key[2 * k + 1] : key[2 * k];
      ts[k] = gr ? (2 * k + 1) : (2 * k);
    }
    tk[9] = key[18];
    ts[9] = 18;
#pragma unroll
    for (int w = 1; w < 10; w <<= 1) {
#pragma unroll
      for (int k = 0; k + w < 10; k += 2 * w) {
        if (tk[k + w] > tk[k]) { tk[k] = tk[k + w]; ts[k] = ts[k + w]; }
      }
    }
    u64 mk = tk[0];
    int mj = lid + (ts[0] << 6);  // winner's bucket index for this lane

    // wave butterfly on (key, bucket index); the 3 swizzles per step are
    // independent -> chain depth is one swizzle latency per step
    for (int off = 32; off; off >>= 1) {
      u64 okey = __shfl_xor(mk, off);
      int oj = __shfl_xor(mj, off);
      if (okey > mk) { mk = okey; mj = oj; }
    }
    if (mk == 0ULL) break;
    if (lid == 0) ok[t] = mk;
    ++t;
    if (t >= NDET) break;

    // suppress: winner box broadcast (uniform LDS read), IoU vs LDS boxes.
    // Winner kill folded in as a static-index predicate (self-IoU also kills,
    // but the predicate guarantees termination independent of rounding).
    float4 p = lc[mj];
    float pa = (p.z - p.x) * (p.w - p.y);
#pragma unroll
    for (int k = 0; k < KMAX; ++k) {
      float4 qq = lc[lid + 64 * k];  // static offset: lid*16 + k*1024
      float lx = fmaxf(p.x, qq.x), ly = fmaxf(p.y, qq.y);
      float rx = fminf(p.z, qq.z), ry = fminf(p.w, qq.w);
      float ww = fmaxf(rx - lx, 0.0f), hh = fmaxf(ry - ly, 0.0f);
      float inter = ww * hh;
      float a2 = (qq.z - qq.x) * (qq.w - qq.y);
      float iou = inter / (pa + a2 - inter + 1e-8f);
      bool kill = (iou > 0.5f) | ((lid + (k << 6)) == mj);
      key[k] = kill ? 0ULL : key[k];
    }
  }
  if (lid == 0) nsel[bc] = t;
}

// ---------------------------------------------------------------------------
// Emit one output row (decode xywh exactly like reference).
// ---------------------------------------------------------------------------
__device__ __forceinline__ void emit_row(float* __restrict__ out,
                                         const float* __restrict__ pred,
                                         const float* __restrict__ anchors,
                                         int b, int t, u64 key, int cls) {
#pragma clang fp contract(off)
  float* o = out + ((size_t)b * NDET + t) * 6;
  if (key == 0ULL) {
    o[0] = 0.f; o[1] = 0.f; o[2] = 0.f; o[3] = 0.f; o[4] = -1.f; o[5] = -1.f;
    return;
  }
  float scv = __uint_as_float((u32)(key >> 32));
  int oiv = (int)(0xFFFFFFFFu - (u32)key);
  const float* pr = pred + ((size_t)b * N_ANCH + oiv) * NPRED;
  const float* a = anchors + (size_t)oiv * 4;
  float b0 = pr[0] * 0.1f, b1 = pr[1] * 0.1f;
  float b2 = pr[2] * 0.2f, b3 = pr[3] * 0.2f;
  float cx = b0 * a[2] + a[0];
  float cy = b1 * a[3] + a[1];
  float w = expf(b2) * a[2];
  float h = expf(b3) * a[3];
  o[0] = cx; o[1] = cy; o[2] = w; o[3] = h;
  o[4] = (float)cls; o[5] = scv;
}

// ---------------------------------------------------------------------------
// K3: per-batch 80-way tournament merge of sorted per-class key sequences.
// Cross-class IoU is exactly 0 (class offset 10000 >> max box extent), so the
// reference's global greedy sequence == merge of per-class sequences by key.
// ---------------------------------------------------------------------------
__global__ void __launch_bounds__(64) k_merge(const u64* __restrict__ keys,
                                              const int* __restrict__ nsel,
                                              const float* __restrict__ pred,
                                              const float* __restrict__ anchors,
                                              float* __restrict__ out) {
  int b = blockIdx.x;
  int lid = threadIdx.x;
  __shared__ u64 lkeys[NCLS * NDET];  // 64000 B
  __shared__ int lcnt[NCLS];
  for (int k = lid; k < NCLS; k += 64) {
    int n = nsel[b * NCLS + k];
    lcnt[k] = (n > NDET) ? NDET : n;
  }
  __syncthreads();
  for (int idx = lid; idx < NCLS * NDET; idx += 64) {
    int c = idx / NDET;
    int k = idx - c * NDET;
    lkeys[idx] = (k < lcnt[c]) ? keys[(size_t)(b * NCLS + c) * NDET + k] : 0ULL;
  }
  __syncthreads();

  int cntA = lcnt[lid];
  int cntB = (lid < 16) ? lcnt[64 + lid] : 0;
  int ptrA = 0, ptrB = 0;
  u64 w1 = 0ULL, w2 = 0ULL;
  int w1c = 0, w2c = 0;
  for (int t = 0; t < NDET; ++t) {
    u64 kA = (ptrA < cntA) ? lkeys[lid * NDET + ptrA] : 0ULL;
    u64 kB = (ptrB < cntB) ? lkeys[(64 + lid) * NDET + ptrB] : 0ULL;
    u64 mk; int mc;
    if (kB > kA) { mk = kB; mc = 64 + lid; } else { mk = kA; mc = lid; }
    for (int off = 32; off; off >>= 1) {
      u64 okk = __shfl_xor(mk, off);
      int oc = __shfl_xor(mc, off);
      if (okk > mk) { mk = okk; mc = oc; }
    }
    if (mk == 0ULL) break;
    if (lid == mc) ptrA++;
    if (lid + 64 == mc) ptrB++;
    if (lid == (t & 63)) {
      if (t < 64) { w1 = mk; w1c = mc; } else { w2 = mk; w2c = mc; }
    }
  }
  emit_row(out, pred, anchors, b, lid, w1, w1c);
  if (lid + 64 < NDET) emit_row(out, pred, anchors, b, lid + 64, w2, w2c);
}

// ---------------------------------------------------------------------------
extern "C" void kernel_launch(void* const* d_in, const int* in_sizes, int n_in,
                              void* d_out, int out_size, void* d_ws, size_t ws_size,
                              hipStream_t stream) {
  const float* pred = (const float*)d_in[1];     // (8, 76725, 84) f32
  const float* anchors = (const float*)d_in[2];  // (76725, 4) f32
  float* out = (float*)d_out;                    // (8, 100, 6) f32

  const int NBUCK = BATCH * NCLS;  // 640

  float4* bk_c = (float4*)d_ws;                     // 640*1216 float4 = 12.45 MB
  u64* keys = (u64*)(bk_c + (size_t)NBUCK * BCAP);  // 640*100 u64
  float* bk_s = (float*)(keys + (size_t)NBUCK * NDET);
  int* bk_oi = (int*)(bk_s + (size_t)NBUCK * BCAP);
  int* nsel = bk_oi + (size_t)NBUCK * BCAP;
  int* cursor = nsel + NBUCK;  // 640 * 16 ints (line-padded)

  hipMemsetAsync(cursor, 0, NBUCK * CURSOR_STRIDE * sizeof(int), stream);

  // 4 lanes per anchor, 64 anchors per 256-thread block
  int nb = (BATCH * N_ANCH + 63) / 64;
  k_decode_scatter<<<nb, 256, 0, stream>>>(pred, anchors, cursor, bk_c, bk_s, bk_oi);
  k_nms_class<<<NBUCK, 64, 0, stream>>>(cursor, bk_c, bk_s, bk_oi, keys, nsel);
  k_merge<<<BATCH, 64, 0, stream>>>(keys, nsel, pred, anchors, out);
}

// Round 5
// 541.416 us; speedup vs baseline: 1.3635x; 1.3635x over previous
//
#include <hip/hip_runtime.h>
#include <math.h>

#define BATCH 8
#define N_ANCH 76725
#define NCLS 80
#define NDET 100
#define NPRED 84
#define NSEG 8        // cursor/storage segments per bucket, selected by blockIdx&7
                      // (~XCD id): same-line atomics then come from one XCD ->
                      // no cross-die line ping-pong (was ~390ns/RMW x 959/line)
#define SEGCAP 192    // per-(bucket,seg) capacity: mean 120, sd 11 -> +6.5 sigma
#define NSORT 2048    // bitonic size >= NSEG*SEGCAP = 1536
#define CURSOR_STRIDE 16  // one counter per 64B line

typedef unsigned long long u64;
typedef unsigned int u32;

// ---------------------------------------------------------------------------
// K1 (fused, coalesced): 4 lanes per anchor. Lane p of a 4-lane group reads
// float4 indices {p, p+4, p+8, ...} of the 84-float row (fully coalesced).
// Per-lane partial top-2 over logits merged to the exact lexicographic
// (logit desc, class asc) top-2 via two shfl_xor steps — bitwise-identical to
// a sequential strict-> scan, including the sigmoid-rounding tie window.
// Leader decodes the box and scatters into segment blockIdx&7 of the
// (batch,class) bucket.
// ---------------------------------------------------------------------------
__global__ void __launch_bounds__(256) k_decode_scatter(
    const float* __restrict__ pred, const float* __restrict__ anchors,
    int* __restrict__ cursor, float4* __restrict__ bk_c,
    float* __restrict__ bk_s, int* __restrict__ bk_oi) {
#pragma clang fp contract(off)
  int lane = threadIdx.x & 63;
  int wave = threadIdx.x >> 6;
  int g = lane >> 2;   // anchor within wave (16 per wave)
  int p = lane & 3;    // sub-lane within anchor group
  int gid = blockIdx.x * 64 + wave * 16 + g;  // 64 anchors per block
  if (gid >= BATCH * N_ANCH) return;
  int b = gid / N_ANCH;
  int i = gid - b * N_ANCH;
  const float4* row = (const float4*)(pred + (size_t)gid * NPRED);

  // per-lane partial top-2 (strict > keeps smallest class index on ties;
  // within a lane, class indices are visited in ascending order)
  float l1 = -3.0e38f, l2 = -3.0e38f;
  int i1 = 0, i2 = 0;
#define UPD(LV, IDX)                                          \
  { float l = (LV); int idx = (IDX);                          \
    if (l > l1) { l2 = l1; i2 = i1; l1 = l; i1 = idx; }       \
    else if (l > l2) { l2 = l; i2 = idx; } }

  float4 bp = make_float4(0.f, 0.f, 0.f, 0.f);
  {
    float4 v = row[p];  // j=0: p==0 gets the box quad, p>0 get class quads
    if (p == 0) {
      bp = v;
    } else {
      int c0 = p * 4 - 4;
      UPD(v.x, c0) UPD(v.y, c0 + 1) UPD(v.z, c0 + 2) UPD(v.w, c0 + 3)
    }
  }
#pragma unroll
  for (int j = 1; j < 5; ++j) {
    int idx = p + 4 * j;
    float4 v = row[idx];
    int c0 = idx * 4 - 4;
    UPD(v.x, c0) UPD(v.y, c0 + 1) UPD(v.z, c0 + 2) UPD(v.w, c0 + 3)
  }
  if (p == 0) {  // tail quad idx=20 (classes 76..79)
    float4 v = row[20];
    UPD(v.x, 76) UPD(v.y, 77) UPD(v.z, 78) UPD(v.w, 79)
  }
#undef UPD

  // exact lex top-2 merge across the 4-lane group (classes are disjoint
  // across lanes, so union-top2 = merge of per-lane sorted top2 pairs)
#pragma unroll
  for (int off = 1; off <= 2; off <<= 1) {
    float ol1 = __shfl_xor(l1, off);
    int   oj1 = __shfl_xor(i1, off);
    float ol2 = __shfl_xor(l2, off);
    int   oj2 = __shfl_xor(i2, off);
    bool aW = (l1 > ol1) || (l1 == ol1 && i1 < oj1);
    float w1 = aW ? l1 : ol1;  int wi1 = aW ? i1 : oj1;
    float ca = aW ? l2 : ol2;  int cai = aW ? i2 : oj2;  // winner's 2nd
    float cb = aW ? ol1 : l1;  int cbi = aW ? oj1 : i1;  // loser's 1st
    bool s2 = (ca > cb) || (ca == cb && cai < cbi);
    l1 = w1; i1 = wi1;
    l2 = s2 ? ca : cb; i2 = s2 ? cai : cbi;
  }

  if (p != 0) return;  // group leader emits

  float conf = 1.0f / (1.0f + expf(-l1));
  int cls = i1;
  if (l1 - l2 < 1e-4f) {  // only window where rounded sigmoids can collide
    float conf2 = 1.0f / (1.0f + expf(-l2));
    if (conf2 > conf) { conf = conf2; cls = i2; }
    else if (conf2 == conf && i2 < i1) { cls = i2; }
  }
  float score = (conf > 0.05f) ? conf : -1.0f;

  // box decode (reference op order, no fma contraction)
  float4 a = *(const float4*)(anchors + (size_t)i * 4);
  float b0 = bp.x * 0.1f, b1 = bp.y * 0.1f, b2 = bp.z * 0.2f, b3 = bp.w * 0.2f;
  float cx = b0 * a.z + a.x;
  float cy = b1 * a.w + a.y;
  float w = expf(b2) * a.z;
  float h = expf(b3) * a.w;
  float offv = (float)cls * 10000.0f;
  float x0 = (cx - 0.5f * w) + offv, y0 = (cy - 0.5f * h) + offv;
  float x1 = (cx + 0.5f * w) + offv, y1 = (cy + 0.5f * h) + offv;

  int bc = b * NCLS + cls;
  int cell = bc * NSEG + (blockIdx.x & (NSEG - 1));
  int slot = atomicAdd(&cursor[cell * CURSOR_STRIDE], 1);
  if (slot < SEGCAP) {
    size_t idxo = (size_t)cell * SEGCAP + slot;
    bk_c[idxo] = make_float4(x0, y0, x1, y1);
    bk_s[idxo] = score;
    bk_oi[idxo] = i;
  }
}

// ---------------------------------------------------------------------------
// K2: per-(batch,class) greedy NMS as SORT + ORDERED SCAN (replaces the
// argmax-suppress loop, whose serial chain cost ~6900 cyc/selection:
// 6-step u64 butterfly + 19-IoU sweep per iteration).
//  Phase 1 (4 waves): stage the bucket's <=1536 (key, slot) pairs + corners
//    into LDS, bitonic-sort 2048 descending by u64 key (score<<32 | ~oidx).
//    Keys are unique (oidx unique), invalid/padding = 0.
//  Phase 2 (wave 0): walk candidates in sorted order; accept iff IoU <= 0.5
//    vs every previously-accepted box. Accepted boxes live in 2 static
//    register slots/lane (<=128 >= NDET); the wave-wide test is one __any.
//    Sorted-scan greedy NMS == argmax-suppress greedy NMS (same accepted
//    set, same order, by induction over the descending key order).
//  IoU bitwise-identical to before: p = accepted box (a1), q = candidate
//    (a2), inter/((pa+qa)-inter+1e-8), contract off.
// ---------------------------------------------------------------------------
__global__ void __launch_bounds__(256, 1) k_nms_class(
    const int* __restrict__ cursor, const float4* __restrict__ bk_c,
    const float* __restrict__ bk_s, const int* __restrict__ bk_oi,
    u64* __restrict__ keys, int* __restrict__ nsel) {
#pragma clang fp contract(off)
  __shared__ u64 skey[NSORT];              // 16 KB
  __shared__ u32 sslot[NSORT];             // 8 KB
  __shared__ float4 lc[NSEG * SEGCAP];     // 24 KB
  int bc = blockIdx.x;
  int tid = threadIdx.x;

  // segment counts/offsets (uniform scalar loads, same on every thread)
  int cnts[NSEG], offs[NSEG];
  int tot = 0;
#pragma unroll
  for (int s = 0; s < NSEG; ++s) {
    int c = cursor[(bc * NSEG + s) * CURSOR_STRIDE];
    c = (c > SEGCAP) ? SEGCAP : c;
    cnts[s] = c;
    offs[s] = tot;
    tot += c;
  }

  // compact segments into LDS
#pragma unroll
  for (int s = 0; s < NSEG; ++s) {
    size_t gbase = (size_t)(bc * NSEG + s) * SEGCAP;
    for (int j = tid; j < cnts[s]; j += 256) {
      int dst = offs[s] + j;
      float sc = bk_s[gbase + j];
      u32 o = (u32)bk_oi[gbase + j];
      skey[dst] = (sc > 0.0f)
                      ? (((u64)__float_as_uint(sc) << 32) |
                         (u64)(0xFFFFFFFFu - o))
                      : 0ULL;
      sslot[dst] = (u32)dst;
      lc[dst] = bk_c[gbase + j];
    }
  }
  for (int j = tot + tid; j < NSORT; j += 256) {
    skey[j] = 0ULL;
    sslot[j] = 0u;
  }

  // bitonic sort, descending by key (66 passes). Pairs (i, i^j) disjoint per
  // pass and each handled by exactly one thread -> race-free with barriers.
  for (int k = 2; k <= NSORT; k <<= 1) {
    for (int j = k >> 1; j > 0; j >>= 1) {
      __syncthreads();
      for (int i = tid; i < NSORT; i += 256) {
        int ixj = i ^ j;
        if (ixj > i) {
          u64 a = skey[i], b = skey[ixj];
          bool desc = ((i & k) == 0);
          bool sw = desc ? (a < b) : (a > b);
          if (sw) {
            skey[i] = b;
            skey[ixj] = a;
            u32 t = sslot[i];
            sslot[i] = sslot[ixj];
            sslot[ixj] = t;
          }
        }
      }
    }
  }
  __syncthreads();
  if (tid >= 64) return;  // waves 1-3 done; LDS persists while wave 0 scans

  int lid = tid;
  float4 accA = make_float4(0.f, 0.f, 0.f, 0.f);  // inert: IoU vs anything = 0
  float4 accB = make_float4(0.f, 0.f, 0.f, 0.f);
  float aA = 0.f, aB = 0.f;
  int na = 0;
  u64* ok = keys + (size_t)bc * NDET;

  for (int idx = 0; idx < NSORT; ++idx) {
    u64 ck = skey[idx];  // uniform broadcast read
    if (ck == 0ULL) break;
    float4 q = lc[sslot[idx]];  // uniform
    float qa = (q.z - q.x) * (q.w - q.y);

    // IoU(accepted p, candidate q) — same operand roles as reference
    float lxA = fmaxf(accA.x, q.x), lyA = fmaxf(accA.y, q.y);
    float rxA = fminf(accA.z, q.z), ryA = fminf(accA.w, q.w);
    float wA = fmaxf(rxA - lxA, 0.0f), hA = fmaxf(ryA - lyA, 0.0f);
    float inA = wA * hA;
    float iouA = inA / (aA + qa - inA + 1e-8f);

    float lxB = fmaxf(accB.x, q.x), lyB = fmaxf(accB.y, q.y);
    float rxB = fminf(accB.z, q.z), ryB = fminf(accB.w, q.w);
    float wB = fmaxf(rxB - lxB, 0.0f), hB = fmaxf(ryB - lyB, 0.0f);
    float inB = wB * hB;
    float iouB = inB / (aB + qa - inB + 1e-8f);

    bool kill = (iouA > 0.5f) || (iouB > 0.5f);
    if (!__any(kill)) {
      if (lid == 0) ok[na] = ck;
      if (na < 64) {
        if (lid == na) { accA = q; aA = qa; }
      } else {
        if (lid == na - 64) { accB = q; aB = qa; }
      }
      ++na;
      if (na >= NDET) break;
    }
  }
  if (lid == 0) nsel[bc] = na;
}

// ---------------------------------------------------------------------------
// Emit one output row (decode xywh exactly like reference).
// ---------------------------------------------------------------------------
__device__ __forceinline__ void emit_row(float* __restrict__ out,
                                         const float* __restrict__ pred,
                                         const float* __restrict__ anchors,
                                         int b, int t, u64 key, int cls) {
#pragma clang fp contract(off)
  float* o = out + ((size_t)b * NDET + t) * 6;
  if (key == 0ULL) {
    o[0] = 0.f; o[1] = 0.f; o[2] = 0.f; o[3] = 0.f; o[4] = -1.f; o[5] = -1.f;
    return;
  }
  float scv = __uint_as_float((u32)(key >> 32));
  int oiv = (int)(0xFFFFFFFFu - (u32)key);
  const float* pr = pred + ((size_t)b * N_ANCH + oiv) * NPRED;
  const float* a = anchors + (size_t)oiv * 4;
  float b0 = pr[0] * 0.1f, b1 = pr[1] * 0.1f;
  float b2 = pr[2] * 0.2f, b3 = pr[3] * 0.2f;
  float cx = b0 * a[2] + a[0];
  float cy = b1 * a[3] + a[1];
  float w = expf(b2) * a[2];
  float h = expf(b3) * a[3];
  o[0] = cx; o[1] = cy; o[2] = w; o[3] = h;
  o[4] = (float)cls; o[5] = scv;
}

// ---------------------------------------------------------------------------
// K3: per-batch 80-way tournament merge of sorted per-class key sequences.
// Cross-class IoU is exactly 0 (class offset 10000 >> max box extent), so the
// reference's global greedy sequence == merge of per-class sequences by key.
// ---------------------------------------------------------------------------
__global__ void __launch_bounds__(64) k_merge(const u64* __restrict__ keys,
                                              const int* __restrict__ nsel,
                                              const float* __restrict__ pred,
                                              const float* __restrict__ anchors,
                                              float* __restrict__ out) {
  int b = blockIdx.x;
  int lid = threadIdx.x;
  __shared__ u64 lkeys[NCLS * NDET];  // 64000 B
  __shared__ int lcnt[NCLS];
  for (int k = lid; k < NCLS; k += 64) {
    int n = nsel[b * NCLS + k];
    lcnt[k] = (n > NDET) ? NDET : n;
  }
  __syncthreads();
  for (int idx = lid; idx < NCLS * NDET; idx += 64) {
    int c = idx / NDET;
    int k = idx - c * NDET;
    lkeys[idx] = (k < lcnt[c]) ? keys[(size_t)(b * NCLS + c) * NDET + k] : 0ULL;
  }
  __syncthreads();

  int cntA = lcnt[lid];
  int cntB = (lid < 16) ? lcnt[64 + lid] : 0;
  int ptrA = 0, ptrB = 0;
  u64 w1 = 0ULL, w2 = 0ULL;
  int w1c = 0, w2c = 0;
  for (int t = 0; t < NDET; ++t) {
    u64 kA = (ptrA < cntA) ? lkeys[lid * NDET + ptrA] : 0ULL;
    u64 kB = (ptrB < cntB) ? lkeys[(64 + lid) * NDET + ptrB] : 0ULL;
    u64 mk; int mc;
    if (kB > kA) { mk = kB; mc = 64 + lid; } else { mk = kA; mc = lid; }
    for (int off = 32; off; off >>= 1) {
      u64 okk = __shfl_xor(mk, off);
      int oc = __shfl_xor(mc, off);
      if (okk > mk) { mk = okk; mc = oc; }
    }
    if (mk == 0ULL) break;
    if (lid == mc) ptrA++;
    if (lid + 64 == mc) ptrB++;
    if (lid == (t & 63)) {
      if (t < 64) { w1 = mk; w1c = mc; } else { w2 = mk; w2c = mc; }
    }
  }
  emit_row(out, pred, anchors, b, lid, w1, w1c);
  if (lid + 64 < NDET) emit_row(out, pred, anchors, b, lid + 64, w2, w2c);
}

// ---------------------------------------------------------------------------
extern "C" void kernel_launch(void* const* d_in, const int* in_sizes, int n_in,
                              void* d_out, int out_size, void* d_ws, size_t ws_size,
                              hipStream_t stream) {
  const float* pred = (const float*)d_in[1];     // (8, 76725, 84) f32
  const float* anchors = (const float*)d_in[2];  // (76725, 4) f32
  float* out = (float*)d_out;                    // (8, 100, 6) f32

  const int NBUCK = BATCH * NCLS;              // 640
  const size_t SLOTS = (size_t)NBUCK * NSEG * SEGCAP;  // 983040

  float4* bk_c = (float4*)d_ws;                 // 15.73 MB
  u64* keys = (u64*)(bk_c + SLOTS);             // 512 KB
  float* bk_s = (float*)(keys + (size_t)NBUCK * NDET);  // 3.93 MB
  int* bk_oi = (int*)(bk_s + SLOTS);            // 3.93 MB
  int* nsel = bk_oi + SLOTS;                    // 2.5 KB
  int* cursor = nsel + NBUCK;                   // 5120 * 16 ints = 328 KB

  hipMemsetAsync(cursor, 0, (size_t)NBUCK * NSEG * CURSOR_STRIDE * sizeof(int),
                 stream);

  // 4 lanes per anchor, 64 anchors per 256-thread block
  int nb = (BATCH * N_ANCH + 63) / 64;
  k_decode_scatter<<<nb, 256, 0, stream>>>(pred, anchors, cursor, bk_c, bk_s, bk_oi);
  k_nms_class<<<NBUCK, 256, 0, stream>>>(cursor, bk_c, bk_s, bk_oi, keys, nsel);
  k_merge<<<BATCH, 64, 0, stream>>>(keys, nsel, pred, anchors, out);
}